// Round 9
// baseline (451.794 us; speedup 1.0000x reference)
//
#include <hip/hip_runtime.h>

// MultiRelGraphTransformer on MI355X — round 9 (r8 + compile fix).
// __builtin_nontemporal_* requires Clang ext_vector_type, not HIP uint4/int4
// (class types). Everything else identical to r8:
// (a) spmm column-split: xcd&1 selects 64-col half -> per-XCD H working
// set 2.56 MB < 4 MB L2; srcs loads + G stores nontemporal to protect H
// residency; single 16B H load/edge/lane with shift/mask bf16 unpack.
// (b) gemm_ln epilogue: scalar residual loads, vectorized store repack
// overlaid in K-loop LDS (33.8 KB, 4 blocks/CU).

#define NNODES 20000
#define NB     4
#define BROWS  (NB * NNODES)   // 80000
#define DN     64
#define DM     128
#define NE     160000
#define CAP    64              // bucket capacity per (relation,dst); Poisson(8)
#define LN_EPS 1e-5f
#define KE     448             // 384 spmm cols + 64 ext cols
#define LDW    88              // K-loop LDS row stride (ushorts): 44 dw -> 2-way free
#define FOW    132             // f32 out tile stride (floats)
#define UOW    136             // bf16 out tile stride (ushorts)

typedef __attribute__((ext_vector_type(8))) short bf16x8;
typedef __attribute__((ext_vector_type(4))) float f32x4;
typedef __attribute__((ext_vector_type(4))) unsigned int u32x4;
typedef __attribute__((ext_vector_type(4))) int i32x4;

__device__ inline float bf2f(unsigned short u) {
    union { unsigned int i; float f; } x; x.i = ((unsigned int)u) << 16; return x.f;
}
__device__ inline unsigned short f2bf(float f) {
    union { float f; unsigned int i; } x; x.f = f;
    unsigned int r = x.i + 0x7FFFu + ((x.i >> 16) & 1u);
    return (unsigned short)(r >> 16);
}
__device__ inline float lo16f(unsigned int u) {
    union { unsigned int i; float f; } x; x.i = u << 16; return x.f;
}
__device__ inline float hi16f(unsigned int u) {
    union { unsigned int i; float f; } x; x.i = u & 0xFFFF0000u; return x.f;
}

// ---------- K1: counting-sort into fixed buckets (cursor = true degree) ----------
__global__ void k_scatter(const int* __restrict__ ei0, const int* __restrict__ ei1,
                          const int* __restrict__ ei2, int* __restrict__ cursor,
                          int* __restrict__ srcs, int* __restrict__ eids) {
    int tid = blockIdx.x * blockDim.x + threadIdx.x;
    if (tid >= 3 * NE) return;
    int r = tid / NE, e = tid - r * NE;
    const int* ei = (r == 0) ? ei0 : ((r == 1) ? ei1 : ei2);
    int src = ei[e], dst = ei[NE + e];
    int p = atomicAdd(&cursor[r * NNODES + dst], 1);
    if (p < CAP) {
        srcs[(r * NNODES + dst) * CAP + p] = src;
        if (r < 2) eids[(r * NNODES + dst) * CAP + p] = e;
    }
}

// ---------- K2: S[r][n][16] = sum of ea_r over incoming edges (bucket walk) ----------
__global__ __launch_bounds__(256) void k_sgather(const int* __restrict__ deg,
                                                 const int* __restrict__ eids,
                                                 const float* __restrict__ ea0,
                                                 const float* __restrict__ ea1,
                                                 float* __restrict__ S) {
    int task = blockIdx.x * 4 + (threadIdx.x >> 6);   // 0 .. 2*NNODES-1
    int r = task / NNODES;
    const float* ea = r ? ea1 : ea0;
    int lane = threadIdx.x & 63;
    int k = lane & 15, sub = lane >> 4;
    int dg = deg[task]; if (dg > CAP) dg = CAP;
    const int* bk = eids + (size_t)task * CAP;
    float acc = 0.f;
    for (int j = sub; j < dg; j += 4) {
        int e = bk[j];
        acc += ea[e * 16 + k];
    }
    acc += __shfl_xor(acc, 16, 64);
    acc += __shfl_xor(acc, 32, 64);
    if (lane < 16) S[(size_t)task * 16 + k] = acc;
}

// ---------- K3: build Wt[2][128][448] (transposed node_W + ext rows) and Wp[128][64] ----------
__global__ __launch_bounds__(256) void k_wprep(const float* __restrict__ nW,
                                               const float* __restrict__ nb,
                                               const float* __restrict__ eW,
                                               const float* __restrict__ eb,
                                               const float* __restrict__ inW,
                                               unsigned short* __restrict__ Wt,
                                               unsigned short* __restrict__ Wp) {
    int lin = blockIdx.x * 256 + threadIdx.x;    // 2*128*448 + 128*64 = 122880
    if (lin < 2 * 128 * KE) {
        int l = lin / (128 * KE);
        int rem = lin - l * 128 * KE;
        int n = rem / KE, k = rem - n * KE;
        float v;
        if (k < 384) {
            int r = k >> 7, kk = k & 127;
            v = nW[(((size_t)(l * 3 + r) * 128) + kk) * 128 + n];
        } else {
            int e = k - 384;
            if (e < 3) {
                v = nb[(l * 3 + e) * DM + n];
                if (e < 2) v += eb[(l * 2 + e) * DM + n];
            } else if (e < 35) {
                int r2 = (e - 3) >> 4, j = (e - 3) & 15;
                v = eW[((size_t)((l * 2 + r2) * 16 + j)) * DM + n];
            } else v = 0.f;
        }
        Wt[lin] = f2bf(v);
    } else {
        int i = lin - 2 * 128 * KE;
        int n = i >> 6, k = i & 63;
        Wp[n * 64 + k] = f2bf(inW[(size_t)k * DM + n]);
    }
}

// ---------- K4: input projection HB = bf16(node_feat @ in_W + in_b), MFMA ----------
__global__ __launch_bounds__(256) void k_proj(const float* __restrict__ X,
                                              const unsigned short* __restrict__ Wp,  // [128][64]
                                              const float* __restrict__ bias,
                                              unsigned short* __restrict__ HB) {
    __shared__ __align__(16) unsigned char smem[33792];
    unsigned short* As = (unsigned short*)smem;              // [64][LDW]
    unsigned short* Bs = (unsigned short*)(smem + 11264);    // [128][LDW]
    unsigned short* UO = (unsigned short*)smem;              // [64][UOW] (epilogue)
    int t = threadIdx.x;
    int m0 = blockIdx.x * 64;
#pragma unroll
    for (int i = 0; i < 4; ++i) {
        int lin = t + 256 * i;
        int row = lin >> 4, seg = lin & 15;
        float4 v = *(const float4*)(X + (size_t)(m0 + row) * DN + seg * 4);
        ushort4 h; h.x = f2bf(v.x); h.y = f2bf(v.y); h.z = f2bf(v.z); h.w = f2bf(v.w);
        *(ushort4*)&As[row * LDW + seg * 4] = h;
    }
#pragma unroll
    for (int i = 0; i < 4; ++i) {
        int lin = t + 256 * i;
        int row = lin >> 3, seg = lin & 7;
        *(uint4*)&Bs[row * LDW + seg * 8] = *(const uint4*)(Wp + (size_t)row * 64 + seg * 8);
    }
    __syncthreads();
    int w = t >> 6, lane = t & 63;
    int q = lane >> 4, lm = lane & 15;
    f32x4 acc[8];
#pragma unroll
    for (int ct = 0; ct < 8; ++ct) acc[ct] = (f32x4){0.f, 0.f, 0.f, 0.f};
#pragma unroll
    for (int kt = 0; kt < 2; ++kt) {
        bf16x8 a = *(const bf16x8*)&As[(w * 16 + lm) * LDW + kt * 32 + q * 8];
#pragma unroll
        for (int ct = 0; ct < 8; ++ct) {
            bf16x8 bf = *(const bf16x8*)&Bs[(ct * 16 + lm) * LDW + kt * 32 + q * 8];
            acc[ct] = __builtin_amdgcn_mfma_f32_16x16x32_bf16(a, bf, acc[ct], 0, 0, 0);
        }
    }
    __syncthreads();
#pragma unroll
    for (int reg = 0; reg < 4; ++reg) {
        int rl = w * 16 + q * 4 + reg;
#pragma unroll
        for (int ct = 0; ct < 8; ++ct) {
            int col = ct * 16 + lm;
            UO[rl * UOW + col] = f2bf(acc[ct][reg] + bias[col]);
        }
    }
    __syncthreads();
#pragma unroll
    for (int i = 0; i < 4; ++i) {
        int lin = t + 256 * i;
        int row = lin >> 4, seg = lin & 15;
        *(uint4*)(HB + (size_t)(m0 + row) * DM + seg * 8) = *(uint4*)&UO[row * UOW + seg * 8];
    }
}

// ---------- K5: SpMM, column-split across XCDs ----------
// blk&7 = xcd: batch = xcd>>1, col-half = xcd&1 -> per-XCD H set 2.56 MB (L2-fit).
// 256 thr = 32 nodes x 8 lanes; 16 B H load per edge per lane.
__global__ __launch_bounds__(256) void k_spmm(const unsigned short* __restrict__ HB,
                                              const int* __restrict__ deg,
                                              const int* __restrict__ srcs,
                                              const float* __restrict__ S,
                                              unsigned short* __restrict__ G) {
    int blk = blockIdx.x;                      // 5000
    int s = blk & 7;
    int bb = s >> 1, half = s & 1;
    int idx = blk >> 3;                        // [0,625)
    int n = idx * 32 + (threadIdx.x >> 3);
    int lane8 = threadIdx.x & 7;
    int cb = half * 64 + lane8 * 8;            // ushort offset into H row
    const unsigned short* Hb = HB + (size_t)bb * NNODES * DM;
    size_t rowbase = ((size_t)(bb * NNODES + n)) * KE;
    int dt[3];
#pragma unroll
    for (int r = 0; r < 3; ++r) {
        dt[r] = deg[r * NNODES + n];
        int dg = dt[r] > CAP ? CAP : dt[r];
        const int* bk = srcs + (size_t)(r * NNODES + n) * CAP;
        float a[8];
#pragma unroll
        for (int j = 0; j < 8; ++j) a[j] = 0.f;
        int j = 0;
        for (; j + 3 < dg; j += 4) {
            i32x4 s4 = __builtin_nontemporal_load((const i32x4*)&bk[j]);
            u32x4 v0 = *(const u32x4*)(Hb + (size_t)s4.x * DM + cb);
            u32x4 v1 = *(const u32x4*)(Hb + (size_t)s4.y * DM + cb);
            u32x4 v2 = *(const u32x4*)(Hb + (size_t)s4.z * DM + cb);
            u32x4 v3 = *(const u32x4*)(Hb + (size_t)s4.w * DM + cb);
            a[0] += lo16f(v0.x) + lo16f(v1.x) + lo16f(v2.x) + lo16f(v3.x);
            a[1] += hi16f(v0.x) + hi16f(v1.x) + hi16f(v2.x) + hi16f(v3.x);
            a[2] += lo16f(v0.y) + lo16f(v1.y) + lo16f(v2.y) + lo16f(v3.y);
            a[3] += hi16f(v0.y) + hi16f(v1.y) + hi16f(v2.y) + hi16f(v3.y);
            a[4] += lo16f(v0.z) + lo16f(v1.z) + lo16f(v2.z) + lo16f(v3.z);
            a[5] += hi16f(v0.z) + hi16f(v1.z) + hi16f(v2.z) + hi16f(v3.z);
            a[6] += lo16f(v0.w) + lo16f(v1.w) + lo16f(v2.w) + lo16f(v3.w);
            a[7] += hi16f(v0.w) + hi16f(v1.w) + hi16f(v2.w) + hi16f(v3.w);
        }
        for (; j < dg; ++j) {
            int s0 = bk[j];
            u32x4 v0 = *(const u32x4*)(Hb + (size_t)s0 * DM + cb);
            a[0] += lo16f(v0.x); a[1] += hi16f(v0.x);
            a[2] += lo16f(v0.y); a[3] += hi16f(v0.y);
            a[4] += lo16f(v0.z); a[5] += hi16f(v0.z);
            a[6] += lo16f(v0.w); a[7] += hi16f(v0.w);
        }
        u32x4 o;
        o.x = (unsigned int)f2bf(a[0]) | ((unsigned int)f2bf(a[1]) << 16);
        o.y = (unsigned int)f2bf(a[2]) | ((unsigned int)f2bf(a[3]) << 16);
        o.z = (unsigned int)f2bf(a[4]) | ((unsigned int)f2bf(a[5]) << 16);
        o.w = (unsigned int)f2bf(a[6]) | ((unsigned int)f2bf(a[7]) << 16);
        __builtin_nontemporal_store(o, (u32x4*)(G + rowbase + r * 128 + cb));
    }
    // ext cols: this half writes ext[half*32 .. half*32+32), 4 lanes x 8 cols
    if (lane8 < 4) {
        unsigned short ev[8];
#pragma unroll
        for (int j = 0; j < 8; ++j) {
            int kk = half * 32 + lane8 * 8 + j;
            float v;
            if (kk < 3)       v = (float)dt[kk];
            else if (kk < 19) v = S[((size_t)(0 * NNODES + n)) * 16 + (kk - 3)];
            else if (kk < 35) v = S[((size_t)(1 * NNODES + n)) * 16 + (kk - 19)];
            else              v = 0.f;
            ev[j] = f2bf(v);
        }
        u32x4 o;
        o.x = (unsigned int)ev[0] | ((unsigned int)ev[1] << 16);
        o.y = (unsigned int)ev[2] | ((unsigned int)ev[3] << 16);
        o.z = (unsigned int)ev[4] | ((unsigned int)ev[5] << 16);
        o.w = (unsigned int)ev[6] | ((unsigned int)ev[7] << 16);
        __builtin_nontemporal_store(o, (u32x4*)(G + rowbase + 384 + half * 32 + lane8 * 8));
    }
}

// ---------- K6: bf16 MFMA GEMM [64x448]@[448x128] + residual + ReLU + LN ----------
// Scalar residual loads (coalesce fine per r6/r7 A/B); vectorized output via
// LDS repack overlaid on K-loop LDS (33.8 KB total -> 4 blocks/CU).
__global__ __launch_bounds__(256) void k_gemm_ln(const unsigned short* __restrict__ G,   // [BROWS][448]
                                                 const unsigned short* __restrict__ Wt,  // [128][448]
                                                 unsigned short* HB,
                                                 const float* __restrict__ lng,
                                                 const float* __restrict__ lnb,
                                                 float* __restrict__ out, int write_f32) {
    __shared__ __align__(16) unsigned char smem[33792];
    unsigned short* Gs = (unsigned short*)smem;              // [64][LDW]  K-loop
    unsigned short* Ws = (unsigned short*)(smem + 11264);    // [128][LDW] K-loop
    float*          FO = (float*)smem;                       // [64][FOW]  epilogue f32
    unsigned short* UO = (unsigned short*)smem;              // [64][UOW]  epilogue bf16
    int t = threadIdx.x;
    int m0 = blockIdx.x * 64;
    int w = t >> 6, lane = t & 63;
    int q = lane >> 4, lm = lane & 15;

    f32x4 acc[8];
#pragma unroll
    for (int ct = 0; ct < 8; ++ct) acc[ct] = (f32x4){0.f, 0.f, 0.f, 0.f};

    for (int kc = 0; kc < 7; ++kc) {
#pragma unroll
        for (int i = 0; i < 2; ++i) {
            int lin = t + 256 * i;
            int row = lin >> 3, seg = lin & 7;
            u32x4 v = __builtin_nontemporal_load(
                (const u32x4*)(G + (size_t)(m0 + row) * KE + kc * 64 + seg * 8));
            *(u32x4*)&Gs[row * LDW + seg * 8] = v;
        }
#pragma unroll
        for (int i = 0; i < 4; ++i) {
            int lin = t + 256 * i;
            int row = lin >> 3, seg = lin & 7;
            *(uint4*)&Ws[row * LDW + seg * 8] =
                *(const uint4*)(Wt + (size_t)row * KE + kc * 64 + seg * 8);
        }
        __syncthreads();
#pragma unroll
        for (int kt = 0; kt < 2; ++kt) {
            bf16x8 a = *(const bf16x8*)&Gs[(w * 16 + lm) * LDW + kt * 32 + q * 8];
#pragma unroll
            for (int ct = 0; ct < 8; ++ct) {
                bf16x8 bf = *(const bf16x8*)&Ws[(ct * 16 + lm) * LDW + kt * 32 + q * 8];
                acc[ct] = __builtin_amdgcn_mfma_f32_16x16x32_bf16(a, bf, acc[ct], 0, 0, 0);
            }
        }
        __syncthreads();
    }

    float gc[8], bc[8];
#pragma unroll
    for (int ct = 0; ct < 8; ++ct) {
        int col = ct * 16 + lm;
        gc[ct] = lng[col]; bc[ct] = lnb[col];
    }
#pragma unroll
    for (int reg = 0; reg < 4; ++reg) {
        int rl = w * 16 + q * 4 + reg;
        size_t row = (size_t)m0 + rl;
        float xv[8];
        float s1 = 0.f, s2 = 0.f;
#pragma unroll
        for (int ct = 0; ct < 8; ++ct) {
            int col = ct * 16 + lm;
            float h = bf2f(HB[row * DM + col]);
            float v = h + fmaxf(acc[ct][reg], 0.f);
            xv[ct] = v; s1 += v; s2 += v * v;
        }
#pragma unroll
        for (int m = 1; m <= 8; m <<= 1) {
            s1 += __shfl_xor(s1, m, 64);
            s2 += __shfl_xor(s2, m, 64);
        }
        float mu  = s1 * (1.f / 128.f);
        float var = s2 * (1.f / 128.f) - mu * mu;
        float inv = rsqrtf(var + LN_EPS);
        if (write_f32) {
#pragma unroll
            for (int ct = 0; ct < 8; ++ct) {
                int col = ct * 16 + lm;
                FO[rl * FOW + col] = (xv[ct] - mu) * inv * gc[ct] + bc[ct];
            }
        } else {
#pragma unroll
            for (int ct = 0; ct < 8; ++ct) {
                int col = ct * 16 + lm;
                UO[rl * UOW + col] = f2bf((xv[ct] - mu) * inv * gc[ct] + bc[ct]);
            }
        }
    }
    __syncthreads();
    if (write_f32) {
#pragma unroll
        for (int i = 0; i < 8; ++i) {
            int lin = t + 256 * i;
            int row = lin >> 5, seg = lin & 31;
            *(float4*)(out + (size_t)(m0 + row) * DM + seg * 4) = *(float4*)&FO[row * FOW + seg * 4];
        }
    } else {
#pragma unroll
        for (int i = 0; i < 4; ++i) {
            int lin = t + 256 * i;
            int row = lin >> 4, seg = lin & 15;
            *(uint4*)(HB + (size_t)(m0 + row) * DM + seg * 8) = *(uint4*)&UO[row * UOW + seg * 8];
        }
    }
}

extern "C" void kernel_launch(void* const* d_in, const int* in_sizes, int n_in,
                              void* d_out, int out_size, void* d_ws, size_t ws_size,
                              hipStream_t stream) {
    const float* node_feat = (const float*)d_in[0];
    const float* in_W   = (const float*)d_in[1];
    const float* in_b   = (const float*)d_in[2];
    const float* node_W = (const float*)d_in[3];   // [2][3][128][128]
    const float* node_b = (const float*)d_in[4];   // [2][3][128]
    const float* edge_W = (const float*)d_in[5];   // [2][2][16][128]
    const float* edge_b = (const float*)d_in[6];   // [2][2][128]
    const float* ln_g   = (const float*)d_in[7];   // [2][128]
    const float* ln_b   = (const float*)d_in[8];   // [2][128]
    const float* ea0    = (const float*)d_in[9];
    const float* ea1    = (const float*)d_in[10];
    const int*   ei0    = (const int*)d_in[11];
    const int*   ei1    = (const int*)d_in[12];
    const int*   ei2    = (const int*)d_in[13];
    float* out = (float*)d_out;

    char* ws = (char*)d_ws;
    size_t off = 0;
    auto alloc = [&](size_t bytes) -> void* {
        void* p = ws + off;
        off = (off + bytes + 255) & ~(size_t)255;
        return p;
    };
    unsigned short* HB     = (unsigned short*)alloc((size_t)BROWS * DM * 2);   // 20.5 MB
    unsigned short* G      = (unsigned short*)alloc((size_t)BROWS * KE * 2);   // 71.7 MB
    int*            cursor = (int*)alloc((size_t)3 * NNODES * 4);              // zeroed
    float*          S      = (float*)alloc((size_t)2 * NNODES * 16 * 4);
    int*            srcs   = (int*)alloc((size_t)3 * NNODES * CAP * 4);        // 15.4 MB
    int*            eids   = (int*)alloc((size_t)2 * NNODES * CAP * 4);        // 10.2 MB
    unsigned short* Wt     = (unsigned short*)alloc((size_t)2 * 128 * KE * 2);
    unsigned short* Wp     = (unsigned short*)alloc((size_t)128 * 64 * 2);

    (void)hipMemsetAsync(cursor, 0, (size_t)3 * NNODES * 4, stream);

    k_scatter<<<(3 * NE + 255) / 256, 256, 0, stream>>>(ei0, ei1, ei2, cursor, srcs, eids);
    k_sgather<<<(2 * NNODES) / 4, 256, 0, stream>>>(cursor, eids, ea0, ea1, S);
    k_wprep<<<480, 256, 0, stream>>>(node_W, node_b, edge_W, edge_b, in_W, Wt, Wp);
    k_proj<<<BROWS / 64, 256, 0, stream>>>(node_feat, Wp, in_b, HB);

    for (int l = 0; l < 2; ++l) {
        k_spmm<<<5000, 256, 0, stream>>>(HB, cursor, srcs, S, G);
        k_gemm_ln<<<BROWS / 64, 256, 0, stream>>>(G, Wt + (size_t)l * 128 * KE, HB,
                                                  ln_g + (size_t)l * DM, ln_b + (size_t)l * DM,
                                                  out, l == 1);
    }
}